// Round 1
// baseline (1616.344 us; speedup 1.0000x reference)
//
#include <hip/hip_runtime.h>
#include <math.h>

static constexpr int NB = 2, NN = 256, HH = 256, DD = 64, LL = 6;

typedef __attribute__((ext_vector_type(8))) short bf16x8;
typedef __attribute__((ext_vector_type(4))) float f32x4;

__device__ __forceinline__ float fsilu(float v) { return v / (1.0f + __expf(-v)); }

__device__ __forceinline__ unsigned short f2bf(float f) {
    union { float f; unsigned int u; } x; x.f = f;
    unsigned int r = x.u + 0x7fffu + ((x.u >> 16) & 1u);
    return (unsigned short)(r >> 16);
}

// ---------------------------------------------------------------- convert
// ew2T[l][col][k] = bf16(ew2[l][k][col]); same for cw1. k fastest -> coalesced write.
__global__ void k_convert(const float* __restrict__ ew2, const float* __restrict__ cw1,
                          unsigned short* __restrict__ ew2T, unsigned short* __restrict__ cw1T) {
    int idx = blockIdx.x * blockDim.x + threadIdx.x;
    const int total = LL * HH * HH;
    if (idx >= total) return;
    int l = idx / (HH * HH);
    int rem = idx - l * (HH * HH);
    int col = rem >> 8;
    int k = rem & 255;
    ew2T[idx] = f2bf(ew2[(l * HH + k) * HH + col]);
    cw1T[idx] = f2bf(cw1[(l * HH + k) * HH + col]);
}

// ---------------------------------------------------------------- encoder (+time emb, x init)
__global__ __launch_bounds__(256) void k_encoder(
    const float* __restrict__ coords, const float* __restrict__ feats, const float* __restrict__ t,
    const float* __restrict__ pw1, const float* __restrict__ pb1,
    const float* __restrict__ pw2, const float* __restrict__ pb2,
    const float* __restrict__ pw3, const float* __restrict__ pb3,
    const float* __restrict__ tw1, const float* __restrict__ tb1,
    const float* __restrict__ tw2, const float* __restrict__ tb2,
    float* __restrict__ h, float* __restrict__ x) {
    __shared__ float spin[4][68];
    __shared__ float sha[4][HH];
    __shared__ float shb[4][HH];
    __shared__ float ste1[HH];
    int tid = threadIdx.x;
    int base = blockIdx.x * 4;
    int b = base / NN;

    for (int r = 0; r < 4; ++r) {
        int row = base + r;
        if (tid < 3) spin[r][tid] = coords[row * 3 + tid];
        if (tid < DD) spin[r][3 + tid] = feats[row * DD + tid];
    }
    float tv = t[b];
    ste1[tid] = fmaxf(tv * tw1[tid] + tb1[tid], 0.0f);
    if (tid < 12) {
        int r = tid / 3, c = tid % 3;
        x[(base + r) * 3 + c] = coords[(base + r) * 3 + c];
    }
    __syncthreads();

    // layer 1: 67 -> H
    float a0 = pb1[tid], a1 = a0, a2 = a0, a3 = a0;
    for (int c = 0; c < 67; ++c) {
        float w = pw1[c * HH + tid];
        a0 += spin[0][c] * w; a1 += spin[1][c] * w; a2 += spin[2][c] * w; a3 += spin[3][c] * w;
    }
    sha[0][tid] = fmaxf(a0, 0.f); sha[1][tid] = fmaxf(a1, 0.f);
    sha[2][tid] = fmaxf(a2, 0.f); sha[3][tid] = fmaxf(a3, 0.f);
    __syncthreads();
    // layer 2
    a0 = pb2[tid]; a1 = a0; a2 = a0; a3 = a0;
    for (int c = 0; c < HH; ++c) {
        float w = pw2[c * HH + tid];
        a0 += sha[0][c] * w; a1 += sha[1][c] * w; a2 += sha[2][c] * w; a3 += sha[3][c] * w;
    }
    shb[0][tid] = fmaxf(a0, 0.f); shb[1][tid] = fmaxf(a1, 0.f);
    shb[2][tid] = fmaxf(a2, 0.f); shb[3][tid] = fmaxf(a3, 0.f);
    __syncthreads();
    // layer 3 + te2
    a0 = pb3[tid]; a1 = a0; a2 = a0; a3 = a0;
    float te = tb2[tid];
    for (int c = 0; c < HH; ++c) {
        float w = pw3[c * HH + tid];
        a0 += shb[0][c] * w; a1 += shb[1][c] * w; a2 += shb[2][c] * w; a3 += shb[3][c] * w;
        te += ste1[c] * tw2[c * HH + tid];
    }
    h[(base + 0) * HH + tid] = fmaxf(a0, 0.f) + te;
    h[(base + 1) * HH + tid] = fmaxf(a1, 0.f) + te;
    h[(base + 2) * HH + tid] = fmaxf(a2, 0.f) + te;
    h[(base + 3) * HH + tid] = fmaxf(a3, 0.f) + te;
}

// ---------------------------------------------------------------- LayerNorm + Ai/Aj
// one wave per row (4 rows/block). Ai includes eb1 bias.
__global__ __launch_bounds__(256) void k_ln_aiaj(
    const float* __restrict__ h, const float* __restrict__ g, const float* __restrict__ bta,
    const float* __restrict__ ew1l, const float* __restrict__ eb1l,
    float* __restrict__ hn, float* __restrict__ Ai, float* __restrict__ Aj) {
    __shared__ float shn[4][HH];
    int tid = threadIdx.x, w = tid >> 6, lane = tid & 63;
    int base = blockIdx.x * 4;
    int row = base + w;

    float v[4];
    #pragma unroll
    for (int q = 0; q < 4; ++q) v[q] = h[row * HH + lane + 64 * q];
    float s = v[0] + v[1] + v[2] + v[3];
    #pragma unroll
    for (int m = 1; m < 64; m <<= 1) s += __shfl_xor(s, m);
    float mu = s * (1.0f / HH);
    float var = 0.f;
    #pragma unroll
    for (int q = 0; q < 4; ++q) { v[q] -= mu; var += v[q] * v[q]; }
    #pragma unroll
    for (int m = 1; m < 64; m <<= 1) var += __shfl_xor(var, m);
    float rstd = rsqrtf(var * (1.0f / HH) + 1e-5f);
    #pragma unroll
    for (int q = 0; q < 4; ++q) {
        int k = lane + 64 * q;
        float hv = v[q] * rstd * g[k] + bta[k];
        shn[w][k] = hv;
        hn[row * HH + k] = hv;
    }
    __syncthreads();

    float ai0 = eb1l[tid], ai1 = ai0, ai2 = ai0, ai3 = ai0;
    float aj0 = 0.f, aj1 = 0.f, aj2 = 0.f, aj3 = 0.f;
    for (int c = 0; c < HH; ++c) {
        float wi = ew1l[c * HH + tid];
        float wj = ew1l[(HH + c) * HH + tid];
        float s0 = shn[0][c], s1 = shn[1][c], s2 = shn[2][c], s3 = shn[3][c];
        ai0 += s0 * wi; ai1 += s1 * wi; ai2 += s2 * wi; ai3 += s3 * wi;
        aj0 += s0 * wj; aj1 += s1 * wj; aj2 += s2 * wj; aj3 += s3 * wj;
    }
    Ai[(base + 0) * HH + tid] = ai0; Aj[(base + 0) * HH + tid] = aj0;
    Ai[(base + 1) * HH + tid] = ai1; Aj[(base + 1) * HH + tid] = aj1;
    Ai[(base + 2) * HH + tid] = ai2; Aj[(base + 2) * HH + tid] = aj2;
    Ai[(base + 3) * HH + tid] = ai3; Aj[(base + 3) * HH + tid] = aj3;
}

// ---------------------------------------------------------------- fused edge pipeline (MFMA)
// one block per (b,i): for all j, s=silu(Ai+Aj+d2*wd) -> m=silu(s@ew2) -> c=silu(m@cw1),
// cw=c.cw2+cb2 ; magg[i]=sum_j m ; xdelta[i]=mean_j rel*cw
__global__ __launch_bounds__(256, 2) void k_edge(
    const float* __restrict__ x, const float* __restrict__ Ai, const float* __restrict__ Aj,
    const float* __restrict__ wd, const float* __restrict__ eb2v,
    const unsigned short* __restrict__ ew2T, const unsigned short* __restrict__ cw1T,
    const float* __restrict__ cb1v, const float* __restrict__ cw2v, const float* __restrict__ cb2p,
    float* __restrict__ magg, float* __restrict__ xdelta) {
    __shared__ float sAi[HH], swd[HH], seb2[HH], scb1[HH], scw2[HH];
    __shared__ float srel[64][3];
    __shared__ float sd2[64];
    __shared__ float cwpart[4][64];
    __shared__ unsigned short s_tile[64 * 256];  // bf16, XOR-swizzled rows of 512B
    __shared__ unsigned short m_tile[64 * 256];

    int tid = threadIdx.x, wv = tid >> 6, lane = tid & 63;
    int bi = blockIdx.x;
    int b = bi >> 8, i = bi & 255;
    int ni = b * NN + i;

    sAi[tid] = Ai[ni * HH + tid];
    swd[tid] = wd[tid];
    seb2[tid] = eb2v[tid];
    scb1[tid] = cb1v[tid];
    scw2[tid] = cw2v[tid];
    float xi0 = x[ni * 3 + 0], xi1 = x[ni * 3 + 1], xi2 = x[ni * 3 + 2];
    float cb2 = cb2p[0];

    float mg[4] = {0.f, 0.f, 0.f, 0.f};
    float xd0 = 0.f, xd1 = 0.f, xd2 = 0.f;
    int wc = wv * 64;

    for (int jc = 0; jc < 4; ++jc) {
        int j0 = jc * 64;
        __syncthreads();
        if (tid < 64) {
            int j = b * NN + j0 + tid;
            float rx = xi0 - x[j * 3 + 0];
            float ry = xi1 - x[j * 3 + 1];
            float rz = xi2 - x[j * 3 + 2];
            srel[tid][0] = rx; srel[tid][1] = ry; srel[tid][2] = rz;
            sd2[tid] = rx * rx + ry * ry + rz * rz;
        }
        __syncthreads();

        // ---- phase 1: s tile (64 x 256 bf16)
        for (int it = 0; it < 8; ++it) {
            int task = it * 256 + tid;
            int row = task >> 5;
            int k0 = (task & 31) << 3;
            float d2v = sd2[row];
            const float* ajp = Aj + ((size_t)(b * NN + j0 + row) * HH + k0);
            bf16x8 sv;
            #pragma unroll
            for (int e = 0; e < 8; ++e) {
                float vy = sAi[k0 + e] + ajp[e] + d2v * swd[k0 + e];
                sv[e] = (short)f2bf(fsilu(vy));
            }
            unsigned off = (unsigned)(row * 512 + k0 * 2) ^ (unsigned)((row & 7) << 4);
            *reinterpret_cast<bf16x8*>(reinterpret_cast<char*>(s_tile) + off) = sv;
        }
        __syncthreads();

        // ---- phase 2: m = silu(s @ ew2 + eb2)  (64 x 256)
        {
            f32x4 acc[4][4];
            #pragma unroll
            for (int rt = 0; rt < 4; ++rt)
                #pragma unroll
                for (int ct = 0; ct < 4; ++ct) acc[rt][ct] = (f32x4){0.f, 0.f, 0.f, 0.f};
            for (int ks = 0; ks < 8; ++ks) {
                int ak = ks * 32 + (lane >> 4) * 8;
                bf16x8 afr[4], bfr[4];
                #pragma unroll
                for (int rt = 0; rt < 4; ++rt) {
                    int row = rt * 16 + (lane & 15);
                    unsigned off = (unsigned)(row * 512 + ak * 2) ^ (unsigned)((row & 7) << 4);
                    afr[rt] = *reinterpret_cast<const bf16x8*>(reinterpret_cast<const char*>(s_tile) + off);
                }
                #pragma unroll
                for (int ct = 0; ct < 4; ++ct) {
                    int col = wc + ct * 16 + (lane & 15);
                    bfr[ct] = *reinterpret_cast<const bf16x8*>(ew2T + (size_t)col * HH + ak);
                }
                #pragma unroll
                for (int rt = 0; rt < 4; ++rt)
                    #pragma unroll
                    for (int ct = 0; ct < 4; ++ct)
                        acc[rt][ct] = __builtin_amdgcn_mfma_f32_16x16x32_bf16(afr[rt], bfr[ct], acc[rt][ct], 0, 0, 0);
            }
            #pragma unroll
            for (int ct = 0; ct < 4; ++ct) {
                int col = wc + ct * 16 + (lane & 15);
                float bias = seb2[col];
                #pragma unroll
                for (int rt = 0; rt < 4; ++rt) {
                    #pragma unroll
                    for (int r = 0; r < 4; ++r) {
                        int row = rt * 16 + (lane >> 4) * 4 + r;
                        float vy = fsilu(acc[rt][ct][r] + bias);
                        mg[ct] += vy;
                        unsigned off = (unsigned)(row * 512 + col * 2) ^ (unsigned)((row & 7) << 4);
                        *reinterpret_cast<unsigned short*>(reinterpret_cast<char*>(m_tile) + off) = f2bf(vy);
                    }
                }
            }
        }
        __syncthreads();

        // ---- phase 3: c = silu(m @ cw1 + cb1); cw = c . cw2 + cb2
        {
            f32x4 acc[4][4];
            #pragma unroll
            for (int rt = 0; rt < 4; ++rt)
                #pragma unroll
                for (int ct = 0; ct < 4; ++ct) acc[rt][ct] = (f32x4){0.f, 0.f, 0.f, 0.f};
            for (int ks = 0; ks < 8; ++ks) {
                int ak = ks * 32 + (lane >> 4) * 8;
                bf16x8 afr[4], bfr[4];
                #pragma unroll
                for (int rt = 0; rt < 4; ++rt) {
                    int row = rt * 16 + (lane & 15);
                    unsigned off = (unsigned)(row * 512 + ak * 2) ^ (unsigned)((row & 7) << 4);
                    afr[rt] = *reinterpret_cast<const bf16x8*>(reinterpret_cast<const char*>(m_tile) + off);
                }
                #pragma unroll
                for (int ct = 0; ct < 4; ++ct) {
                    int col = wc + ct * 16 + (lane & 15);
                    bfr[ct] = *reinterpret_cast<const bf16x8*>(cw1T + (size_t)col * HH + ak);
                }
                #pragma unroll
                for (int rt = 0; rt < 4; ++rt)
                    #pragma unroll
                    for (int ct = 0; ct < 4; ++ct)
                        acc[rt][ct] = __builtin_amdgcn_mfma_f32_16x16x32_bf16(afr[rt], bfr[ct], acc[rt][ct], 0, 0, 0);
            }
            float rs[16];
            #pragma unroll
            for (int q = 0; q < 16; ++q) rs[q] = 0.f;
            #pragma unroll
            for (int ct = 0; ct < 4; ++ct) {
                int col = wc + ct * 16 + (lane & 15);
                float bias = scb1[col], wcw = scw2[col];
                #pragma unroll
                for (int rt = 0; rt < 4; ++rt)
                    #pragma unroll
                    for (int r = 0; r < 4; ++r)
                        rs[rt * 4 + r] += fsilu(acc[rt][ct][r] + bias) * wcw;
            }
            #pragma unroll
            for (int m = 1; m <= 8; m <<= 1)
                #pragma unroll
                for (int q = 0; q < 16; ++q) rs[q] += __shfl_xor(rs[q], m);
            if ((lane & 15) == 0) {
                int rbase = (lane >> 4) * 4;
                #pragma unroll
                for (int rt = 0; rt < 4; ++rt)
                    #pragma unroll
                    for (int r = 0; r < 4; ++r)
                        cwpart[wv][rt * 16 + rbase + r] = rs[rt * 4 + r];
            }
        }
        __syncthreads();
        if (tid < 64) {
            float cwv = cwpart[0][tid] + cwpart[1][tid] + cwpart[2][tid] + cwpart[3][tid] + cb2;
            float p0 = srel[tid][0] * cwv;
            float p1 = srel[tid][1] * cwv;
            float p2 = srel[tid][2] * cwv;
            #pragma unroll
            for (int m = 1; m < 64; m <<= 1) {
                p0 += __shfl_xor(p0, m); p1 += __shfl_xor(p1, m); p2 += __shfl_xor(p2, m);
            }
            xd0 += p0; xd1 += p1; xd2 += p2;
        }
    }

    // magg: reduce across lane>>4 groups, lanes 0..15 write
    #pragma unroll
    for (int ct = 0; ct < 4; ++ct) {
        mg[ct] += __shfl_xor(mg[ct], 16);
        mg[ct] += __shfl_xor(mg[ct], 32);
    }
    if (lane < 16) {
        #pragma unroll
        for (int ct = 0; ct < 4; ++ct)
            magg[(size_t)ni * HH + wc + ct * 16 + lane] = mg[ct];
    }
    if (tid == 0) {
        xdelta[ni * 3 + 0] = xd0 * (1.0f / NN);
        xdelta[ni * 3 + 1] = xd1 * (1.0f / NN);
        xdelta[ni * 3 + 2] = xd2 * (1.0f / NN);
    }
}

// ---------------------------------------------------------------- node update (+x update)
__global__ __launch_bounds__(256) void k_node(
    const float* __restrict__ hn, const float* __restrict__ magg,
    const float* __restrict__ nw1l, const float* __restrict__ nb1l,
    const float* __restrict__ nw2l, const float* __restrict__ nb2l,
    float* __restrict__ h, float* __restrict__ x, const float* __restrict__ xdelta) {
    __shared__ float s2[4][2 * HH];
    __shared__ float su[4][HH];
    int tid = threadIdx.x;
    int base = blockIdx.x * 4;
    for (int r = 0; r < 4; ++r) {
        s2[r][tid] = hn[(base + r) * HH + tid];
        s2[r][HH + tid] = magg[(base + r) * HH + tid];
    }
    if (tid < 12) {
        int r = tid / 3, c = tid % 3;
        x[(base + r) * 3 + c] += xdelta[(base + r) * 3 + c];
    }
    __syncthreads();
    float a0 = nb1l[tid], a1 = a0, a2 = a0, a3 = a0;
    for (int c = 0; c < 2 * HH; ++c) {
        float w = nw1l[c * HH + tid];
        a0 += s2[0][c] * w; a1 += s2[1][c] * w; a2 += s2[2][c] * w; a3 += s2[3][c] * w;
    }
    su[0][tid] = fsilu(a0); su[1][tid] = fsilu(a1); su[2][tid] = fsilu(a2); su[3][tid] = fsilu(a3);
    __syncthreads();
    float d0 = nb2l[tid], d1 = d0, d2 = d0, d3 = d0;
    for (int c = 0; c < HH; ++c) {
        float w = nw2l[c * HH + tid];
        d0 += su[0][c] * w; d1 += su[1][c] * w; d2 += su[2][c] * w; d3 += su[3][c] * w;
    }
    h[(base + 0) * HH + tid] += d0;
    h[(base + 1) * HH + tid] += d1;
    h[(base + 2) * HH + tid] += d2;
    h[(base + 3) * HH + tid] += d3;
}

// ---------------------------------------------------------------- decoder
__global__ __launch_bounds__(256) void k_decoder(
    const float* __restrict__ h,
    const float* __restrict__ dw1, const float* __restrict__ db1,
    const float* __restrict__ dw2, const float* __restrict__ db2,
    const float* __restrict__ dw3, const float* __restrict__ db3,
    float* __restrict__ out) {
    __shared__ float sh[4][HH];
    __shared__ float so1[4][HH];
    __shared__ float so2[4][HH];
    int tid = threadIdx.x;
    int base = blockIdx.x * 4;
    for (int r = 0; r < 4; ++r) sh[r][tid] = h[(base + r) * HH + tid];
    __syncthreads();
    float a0 = db1[tid], a1 = a0, a2 = a0, a3 = a0;
    for (int c = 0; c < HH; ++c) {
        float w = dw1[c * HH + tid];
        a0 += sh[0][c] * w; a1 += sh[1][c] * w; a2 += sh[2][c] * w; a3 += sh[3][c] * w;
    }
    so1[0][tid] = fmaxf(a0, 0.f); so1[1][tid] = fmaxf(a1, 0.f);
    so1[2][tid] = fmaxf(a2, 0.f); so1[3][tid] = fmaxf(a3, 0.f);
    __syncthreads();
    a0 = db2[tid]; a1 = a0; a2 = a0; a3 = a0;
    for (int c = 0; c < HH; ++c) {
        float w = dw2[c * HH + tid];
        a0 += so1[0][c] * w; a1 += so1[1][c] * w; a2 += so1[2][c] * w; a3 += so1[3][c] * w;
    }
    so2[0][tid] = fmaxf(a0, 0.f) + sh[0][tid];
    so2[1][tid] = fmaxf(a1, 0.f) + sh[1][tid];
    so2[2][tid] = fmaxf(a2, 0.f) + sh[2][tid];
    so2[3][tid] = fmaxf(a3, 0.f) + sh[3][tid];
    __syncthreads();
    if (tid < 12) {
        int r = tid / 3, c = tid % 3;
        float acc = db3[c];
        for (int k = 0; k < HH; ++k) acc += so2[r][k] * dw3[k * 3 + c];
        out[(base + r) * 3 + c] = acc;
    }
}

// ---------------------------------------------------------------- launch
extern "C" void kernel_launch(void* const* d_in, const int* in_sizes, int n_in,
                              void* d_out, int out_size, void* d_ws, size_t ws_size,
                              hipStream_t stream) {
    const float* coords = (const float*)d_in[0];
    const float* feats  = (const float*)d_in[1];
    const float* t      = (const float*)d_in[2];
    const float* pe_w1  = (const float*)d_in[3];  const float* pe_b1 = (const float*)d_in[4];
    const float* pe_w2  = (const float*)d_in[5];  const float* pe_b2 = (const float*)d_in[6];
    const float* pe_w3  = (const float*)d_in[7];  const float* pe_b3 = (const float*)d_in[8];
    const float* te_w1  = (const float*)d_in[9];  const float* te_b1 = (const float*)d_in[10];
    const float* te_w2  = (const float*)d_in[11]; const float* te_b2 = (const float*)d_in[12];
    const float* ln_g   = (const float*)d_in[13]; const float* ln_b  = (const float*)d_in[14];
    const float* ew1    = (const float*)d_in[15]; const float* eb1   = (const float*)d_in[16];
    const float* ew2    = (const float*)d_in[17]; const float* eb2   = (const float*)d_in[18];
    const float* cw1    = (const float*)d_in[19]; const float* cb1   = (const float*)d_in[20];
    const float* cw2    = (const float*)d_in[21]; const float* cb2   = (const float*)d_in[22];
    const float* nw1    = (const float*)d_in[23]; const float* nb1   = (const float*)d_in[24];
    const float* nw2    = (const float*)d_in[25]; const float* nb2   = (const float*)d_in[26];
    const float* dec_w1 = (const float*)d_in[27]; const float* dec_b1 = (const float*)d_in[28];
    const float* dec_w2 = (const float*)d_in[29]; const float* dec_b2 = (const float*)d_in[30];
    const float* dec_w3 = (const float*)d_in[31]; const float* dec_b3 = (const float*)d_in[32];

    float* ws = (float*)d_ws;
    const int RN = NB * NN * HH;  // 131072
    float* h      = ws;
    float* hn     = ws + RN;
    float* Ai     = ws + 2 * RN;
    float* Aj     = ws + 3 * RN;
    float* magg   = ws + 4 * RN;
    float* x      = ws + 5 * RN;            // 1536
    float* xdelta = ws + 5 * RN + 2048;     // 1536
    unsigned short* ew2T = (unsigned short*)(ws + 5 * RN + 4096);
    unsigned short* cw1T = ew2T + LL * HH * HH;
    // total: ~2.7 MB f32 + 1.5 MB bf16 ≈ 4.2 MB of d_ws

    k_convert<<<(LL * HH * HH + 511) / 512, 512, 0, stream>>>(ew2, cw1, ew2T, cw1T);
    k_encoder<<<NB * NN / 4, 256, 0, stream>>>(coords, feats, t,
        pe_w1, pe_b1, pe_w2, pe_b2, pe_w3, pe_b3, te_w1, te_b1, te_w2, te_b2, h, x);

    for (int l = 0; l < LL; ++l) {
        k_ln_aiaj<<<NB * NN / 4, 256, 0, stream>>>(h, ln_g + l * HH, ln_b + l * HH,
            ew1 + (size_t)l * 513 * HH, eb1 + l * HH, hn, Ai, Aj);
        k_edge<<<NB * NN, 256, 0, stream>>>(x, Ai, Aj,
            ew1 + ((size_t)l * 513 + 512) * HH, eb2 + l * HH,
            ew2T + (size_t)l * HH * HH, cw1T + (size_t)l * HH * HH,
            cb1 + l * HH, cw2 + l * HH, cb2 + l, magg, xdelta);
        k_node<<<NB * NN / 4, 256, 0, stream>>>(hn, magg,
            nw1 + (size_t)l * 2 * HH * HH, nb1 + l * HH,
            nw2 + (size_t)l * HH * HH, nb2 + l * HH, h, x, xdelta);
    }

    k_decoder<<<NB * NN / 4, 256, 0, stream>>>(h, dec_w1, dec_b1, dec_w2, dec_b2,
                                               dec_w3, dec_b3, (float*)d_out);
}